// Round 1
// baseline (285.826 us; speedup 1.0000x reference)
//
#include <hip/hip_runtime.h>

#define NBATCH 16
#define NP 65536
#define NT 48
#define TH 0.35f

// ---- ws layout (bytes) ----
// 0   : float accf[4]  {loss_l, loss_landm, ce_pos, neg_sum}
// 16  : int   acci[2]  {total_pos, total_poslands}
// 24  : int   npos[16]
// 128 : u64   packed[16*48]      (per-truth best prior, packed argmax)
// 8192: uint  hist1[16*2048]
// 139264: uint hist2[16*2048]
// 270336: float lrank[16*65536]  (4 MB)
#define WS_HIST1 8192
#define WS_HIST2 139264
#define WS_LRANK 270336
#define WS_ZERO  270336   // bytes to zero each launch

__device__ __forceinline__ float sml1(float d) {
    float a = fabsf(d);
    return a < 1.f ? 0.5f * a * a : a - 0.5f;
}

// ---------------- Kernel A: per-truth argmax over priors ----------------
// grid (8 prior-chunks, 6 truth-groups, 16 rows), block 256
__global__ void kA(const float* __restrict__ priors, const float* __restrict__ targets,
                   unsigned long long* __restrict__ packed) {
    const int chunk = blockIdx.x, tg = blockIdx.y, b = blockIdx.z;
    __shared__ float tb[8][5];
    if (threadIdx.x < 8) {
        int t = tg * 8 + threadIdx.x;
        const float* tr = targets + ((size_t)b * NT + t) * 15;
        float x1 = tr[0], y1 = tr[1], x2 = tr[2], y2 = tr[3];
        tb[threadIdx.x][0] = x1; tb[threadIdx.x][1] = y1;
        tb[threadIdx.x][2] = x2; tb[threadIdx.x][3] = y2;
        tb[threadIdx.x][4] = (x2 - x1) * (y2 - y1);
    }
    __syncthreads();
    unsigned long long best[8];
#pragma unroll
    for (int j = 0; j < 8; j++) best[j] = 0ull;
    const int pbase = chunk * 8192;
    for (int i = threadIdx.x; i < 8192; i += 256) {
        const int p = pbase + i;
        const float4 q = reinterpret_cast<const float4*>(priors)[p];
        const float px1 = q.x - q.z * 0.5f, py1 = q.y - q.w * 0.5f;
        const float px2 = q.x + q.z * 0.5f, py2 = q.y + q.w * 0.5f;
        const float areaB = (px2 - px1) * (py2 - py1);
        const unsigned int ip = ~(unsigned int)p;  // so equal iou -> smaller p wins (first occurrence)
#pragma unroll
        for (int j = 0; j < 8; j++) {
            float ix1 = fmaxf(tb[j][0], px1), iy1 = fmaxf(tb[j][1], py1);
            float ix2 = fminf(tb[j][2], px2), iy2 = fminf(tb[j][3], py2);
            float w = fmaxf(ix2 - ix1, 0.f), h = fmaxf(iy2 - iy1, 0.f);
            float inter = w * h;
            float iou = inter / (tb[j][4] + areaB - inter);
            unsigned long long key = ((unsigned long long)__float_as_uint(iou) << 32) | ip;
            if (key > best[j]) best[j] = key;
        }
    }
#pragma unroll
    for (int j = 0; j < 8; j++) {
        unsigned long long v = best[j];
        for (int s = 32; s > 0; s >>= 1) {
            unsigned long long o = __shfl_down(v, s, 64);
            if (o > v) v = o;
        }
        if ((threadIdx.x & 63) == 0)
            atomicMax(&packed[b * NT + tg * 8 + j], v);
    }
}

// ---------------- Kernel C: per-prior match, encode, losses, loss_rank ----------------
// grid (64, 16), block 1024
__global__ __launch_bounds__(1024) void kC(
    const float* __restrict__ loc_data, const float* __restrict__ conf_data,
    const float* __restrict__ landm_data, const float* __restrict__ priors,
    const float* __restrict__ targets, const unsigned long long* __restrict__ packed,
    float* __restrict__ lrank, float* __restrict__ accf, int* __restrict__ acci,
    int* __restrict__ npos) {
    const int b = blockIdx.y;
    const int p = blockIdx.x * 1024 + threadIdx.x;
    __shared__ float tbx1[NT], tby1[NT], tbx2[NT], tby2[NT], tlab[NT];
    __shared__ float tlm[NT][10];
    __shared__ int bp[NT];
    for (int i = threadIdx.x; i < NT * 15; i += 1024) {
        int t = i / 15, f = i - t * 15;
        float v = targets[((size_t)b * NT + t) * 15 + f];
        if (f == 0) tbx1[t] = v;
        else if (f == 1) tby1[t] = v;
        else if (f == 2) tbx2[t] = v;
        else if (f == 3) tby2[t] = v;
        else if (f < 14) tlm[t][f - 4] = v;
        else tlab[t] = v;
    }
    if (threadIdx.x < NT)
        bp[threadIdx.x] = (int)(~(unsigned int)(packed[b * NT + threadIdx.x] & 0xFFFFFFFFull));
    __syncthreads();

    const float4 q = reinterpret_cast<const float4*>(priors)[p];
    const float px1 = q.x - q.z * 0.5f, py1 = q.y - q.w * 0.5f;
    const float px2 = q.x + q.z * 0.5f, py2 = q.y + q.w * 0.5f;
    const float areaB = (px2 - px1) * (py2 - py1);
    float bestov = -1.f; int bt = 0;
    for (int t = 0; t < NT; t++) {
        float tx1 = tbx1[t], ty1 = tby1[t], tx2 = tbx2[t], ty2 = tby2[t];
        float ix1 = fmaxf(tx1, px1), iy1 = fmaxf(ty1, py1);
        float ix2 = fminf(tx2, px2), iy2 = fminf(ty2, py2);
        float w = fmaxf(ix2 - ix1, 0.f), h = fmaxf(iy2 - iy1, 0.f);
        float inter = w * h;
        float areaA = (tx2 - tx1) * (ty2 - ty1);
        float iou = inter / (areaA + areaB - inter);
        if (iou > bestov) { bestov = iou; bt = t; }  // strict > = first-occurrence argmax
    }
    int claimed = -1;
    for (int t = 0; t < NT; t++) if (bp[t] == p) claimed = t;  // ascending: max t wins
    if (claimed >= 0) { bt = claimed; bestov = 2.f; }

    const int confi = (bestov < TH) ? 0 : (int)tlab[bt];  // astype(int32) truncation
    const bool pos = (confi != 0);
    const bool posl = (confi > 0);

    const float2 c2 = reinterpret_cast<const float2*>(conf_data)[(size_t)b * NP + p];
    float m = fmaxf(c2.x, c2.y);
    float lse = m + logf(expf(c2.x - m) + expf(c2.y - m));
    float ce = lse - (pos ? c2.y : c2.x);
    lrank[(size_t)b * NP + p] = pos ? 0.f : ce;

    float sl = 0.f, slm = 0.f, cep = 0.f;
    if (pos) {
        cep = ce;
        float tx1 = tbx1[bt], ty1 = tby1[bt], tx2 = tbx2[bt], ty2 = tby2[bt];
        float gcx = ((tx1 + tx2) * 0.5f - q.x) / (0.1f * q.z);
        float gcy = ((ty1 + ty2) * 0.5f - q.y) / (0.1f * q.w);
        float gw = logf((tx2 - tx1) / q.z) / 0.2f;
        float gh = logf((ty2 - ty1) / q.w) / 0.2f;
        float4 ld = reinterpret_cast<const float4*>(loc_data)[(size_t)b * NP + p];
        sl = sml1(ld.x - gcx) + sml1(ld.y - gcy) + sml1(ld.z - gw) + sml1(ld.w - gh);
    }
    if (posl) {
        const float2* lmd = reinterpret_cast<const float2*>(landm_data + ((size_t)b * NP + p) * 10);
#pragma unroll
        for (int i = 0; i < 5; i++) {
            float2 d = lmd[i];
            float gx = (tlm[bt][2 * i] - q.x) / (0.1f * q.z);
            float gy = (tlm[bt][2 * i + 1] - q.y) / (0.1f * q.w);
            slm += sml1(d.x - gx) + sml1(d.y - gy);
        }
    }
    int cp = pos ? 1 : 0, cpl = posl ? 1 : 0;
    for (int s = 32; s > 0; s >>= 1) {
        sl += __shfl_down(sl, s, 64);
        slm += __shfl_down(slm, s, 64);
        cep += __shfl_down(cep, s, 64);
        cp += __shfl_down(cp, s, 64);
        cpl += __shfl_down(cpl, s, 64);
    }
    __shared__ float rf[48];
    __shared__ int ri[32];
    const int lane = threadIdx.x & 63, w = threadIdx.x >> 6;
    if (lane == 0) { rf[w] = sl; rf[16 + w] = slm; rf[32 + w] = cep; ri[w] = cp; ri[16 + w] = cpl; }
    __syncthreads();
    if (threadIdx.x == 0) {
        float a = 0, bb = 0, c = 0; int d = 0, e = 0;
        for (int i = 0; i < 16; i++) { a += rf[i]; bb += rf[16 + i]; c += rf[32 + i]; d += ri[i]; e += ri[16 + i]; }
        atomicAdd(&accf[0], a);
        atomicAdd(&accf[1], bb);
        atomicAdd(&accf[2], c);
        if (d) { atomicAdd(&acci[0], d); atomicAdd(&npos[b], d); }
        if (e) atomicAdd(&acci[1], e);
    }
}

// ---------------- Kernel D1: level-1 histogram (bits 30..20) ----------------
// grid (16, 16), block 256; 4096 elements per block
__global__ void kD1(const float* __restrict__ lrank, unsigned int* __restrict__ hist1) {
    __shared__ unsigned int h[2048];
    const int b = blockIdx.y;
    for (int i = threadIdx.x; i < 2048; i += 256) h[i] = 0;
    __syncthreads();
    const float* v = lrank + (size_t)b * NP;
    const int base = blockIdx.x * 4096;
    for (int i = threadIdx.x; i < 4096; i += 256) {
        unsigned int u = __float_as_uint(v[base + i]);
        atomicAdd(&h[u >> 20], 1u);
    }
    __syncthreads();
    unsigned int* gh = hist1 + b * 2048;
    for (int i = threadIdx.x; i < 2048; i += 256) {
        unsigned int c = h[i];
        if (c) atomicAdd(&gh[i], c);
    }
}

// find the bin containing the k-th largest (descending scan). block must be 256.
__device__ __forceinline__ void find_bin_256(const unsigned int* __restrict__ gh,
                                             unsigned int k, unsigned int* part,
                                             int* r_bin, unsigned int* r_acc) {
    unsigned int s = 0;
#pragma unroll
    for (int i = 0; i < 8; i++) s += gh[threadIdx.x * 8 + i];
    part[threadIdx.x] = s;
    __syncthreads();
    if (threadIdx.x == 0) {
        unsigned int acc = 0; int g = 255;
        for (; g > 0; --g) { unsigned int pg = part[g]; if (acc + pg >= k) break; acc += pg; }
        int bin = g * 8;
        for (int i = 7; i >= 0; --i) {
            unsigned int c = gh[g * 8 + i];
            if (acc + c >= k) { bin = g * 8 + i; break; }
            acc += c;
        }
        *r_bin = bin; *r_acc = acc;  // acc = count strictly above bin
    }
    __syncthreads();
}

// ---------------- Kernel D3: level-2 histogram (bits 20..9) within level-1 bin ----------------
__global__ void kD3(const float* __restrict__ lrank, const unsigned int* __restrict__ hist1,
                    unsigned int* __restrict__ hist2, const int* __restrict__ npos) {
    const int b = blockIdx.y;
    int k = 7 * npos[b]; if (k > NP - 1) k = NP - 1;
    if (k <= 0) return;
    __shared__ unsigned int part[256];
    __shared__ int sbin;
    __shared__ unsigned int sacc;
    find_bin_256(hist1 + b * 2048, (unsigned int)k, part, &sbin, &sacc);
    __shared__ unsigned int h2[2048];
    for (int i = threadIdx.x; i < 2048; i += 256) h2[i] = 0;
    __syncthreads();
    const float* v = lrank + (size_t)b * NP;
    const int base = blockIdx.x * 4096;
    const unsigned int b1 = (unsigned int)sbin;
    for (int i = threadIdx.x; i < 4096; i += 256) {
        unsigned int u = __float_as_uint(v[base + i]);
        if ((u >> 20) == b1) atomicAdd(&h2[(u >> 9) & 2047], 1u);
    }
    __syncthreads();
    unsigned int* gh2 = hist2 + b * 2048;
    for (int i = threadIdx.x; i < 2048; i += 256) {
        unsigned int c = h2[i];
        if (c) atomicAdd(&gh2[i], c);
    }
}

// ---------------- Kernel D5: selective sum of top-k negatives ----------------
__global__ void kD5(const float* __restrict__ lrank, const unsigned int* __restrict__ hist1,
                    const unsigned int* __restrict__ hist2, const int* __restrict__ npos,
                    float* __restrict__ accf) {
    const int b = blockIdx.y;
    int k = 7 * npos[b]; if (k > NP - 1) k = NP - 1;
    if (k <= 0) return;
    __shared__ unsigned int part[256];
    __shared__ int sbin1, sbin2;
    __shared__ unsigned int sacc1, sacc2;
    find_bin_256(hist1 + b * 2048, (unsigned int)k, part, &sbin1, &sacc1);
    unsigned int k1 = (unsigned int)k - sacc1;
    find_bin_256(hist2 + b * 2048, k1, part, &sbin2, &sacc2);
    unsigned int k2 = k1 - sacc2;
    const unsigned int pfx = (((unsigned int)sbin1) << 11) | (unsigned int)sbin2;  // bits 30..9
    const float* v = lrank + (size_t)b * NP;
    const int base = blockIdx.x * 4096;
    float sum = 0.f;
    for (int i = threadIdx.x; i < 4096; i += 256) {
        float x = v[base + i];
        if ((__float_as_uint(x) >> 9) > pfx) sum += x;
    }
    for (int s = 32; s > 0; s >>= 1) sum += __shfl_down(sum, s, 64);
    __shared__ float wsum[4];
    const int lane = threadIdx.x & 63, w = threadIdx.x >> 6;
    if (lane == 0) wsum[w] = sum;
    __syncthreads();
    if (threadIdx.x == 0) {
        float tot = wsum[0] + wsum[1] + wsum[2] + wsum[3];
        if (blockIdx.x == 0)  // boundary-bin tie contribution, once per row
            tot += (float)k2 * __uint_as_float((pfx << 9) | 256u);
        if (tot != 0.f) atomicAdd(&accf[3], tot);
    }
}

// ---------------- Kernel E: finalize ----------------
__global__ void kE(const float* __restrict__ accf, const int* __restrict__ acci,
                   float* __restrict__ out) {
    if (threadIdx.x == 0) {
        float N = fmaxf((float)acci[0], 1.f);
        float N1 = fmaxf((float)acci[1], 1.f);
        out[0] = accf[0] / N;
        out[1] = (accf[2] + accf[3]) / N;
        out[2] = accf[1] / N1;
    }
}

extern "C" void kernel_launch(void* const* d_in, const int* in_sizes, int n_in,
                              void* d_out, int out_size, void* d_ws, size_t ws_size,
                              hipStream_t stream) {
    const float* loc_data = (const float*)d_in[0];
    const float* conf_data = (const float*)d_in[1];
    const float* landm_data = (const float*)d_in[2];
    const float* priors = (const float*)d_in[3];
    const float* targets = (const float*)d_in[4];
    float* out = (float*)d_out;
    char* ws = (char*)d_ws;
    float* accf = (float*)ws;
    int* acci = (int*)(ws + 16);
    int* npos = (int*)(ws + 24);
    unsigned long long* packed = (unsigned long long*)(ws + 128);
    unsigned int* hist1 = (unsigned int*)(ws + WS_HIST1);
    unsigned int* hist2 = (unsigned int*)(ws + WS_HIST2);
    float* lrank = (float*)(ws + WS_LRANK);

    hipMemsetAsync(d_ws, 0, WS_ZERO, stream);
    kA<<<dim3(8, 6, 16), 256, 0, stream>>>(priors, targets, packed);
    kC<<<dim3(64, 16), 1024, 0, stream>>>(loc_data, conf_data, landm_data, priors, targets,
                                          packed, lrank, accf, acci, npos);
    kD1<<<dim3(16, 16), 256, 0, stream>>>(lrank, hist1);
    kD3<<<dim3(16, 16), 256, 0, stream>>>(lrank, hist1, hist2, npos);
    kD5<<<dim3(16, 16), 256, 0, stream>>>(lrank, hist1, hist2, npos, accf);
    kE<<<1, 64, 0, stream>>>(accf, acci, out);
}

// Round 2
// 263.608 us; speedup vs baseline: 1.0843x; 1.0843x over previous
//
#include <hip/hip_runtime.h>

#define NP 65536
#define NT 48
#define TH 0.35f

// ---- ws layout (bytes) ----
// 0   : float accf[4]  {loss_l, loss_landm, ce_pos, neg_sum}
// 16  : int   acci[2]  {total_pos, total_poslands}
// 24  : int   npos[16]
// 128 : u64   packed[16*48]      (per-truth best prior, packed argmax)
// 8192: uint  hist1[16*2048]
// 139264: uint hist2[16*2048]
// 270336: float lrank[16*65536]  (4 MB)
#define WS_HIST1 8192
#define WS_HIST2 139264
#define WS_LRANK 270336
#define WS_ZERO  270336

__device__ __forceinline__ float sml1(float d) {
    float a = fabsf(d);
    return a < 1.f ? 0.5f * a * a : a - 0.5f;
}

// ---------------- Kernel A: per-truth argmax over priors ----------------
// grid (8 prior-chunks, 6 truth-groups, 16 rows), block 256
// cross-multiplied running max, truths held in SGPRs (uniform loads), one div at end.
__global__ __launch_bounds__(256) void kA(const float* __restrict__ priors,
                                          const float* __restrict__ targets,
                                          unsigned long long* __restrict__ packed) {
    const int chunk = blockIdx.x, tg = blockIdx.y, b = blockIdx.z;
    const float* tb = targets + ((size_t)b * NT + tg * 8) * 15;
    float tx1[8], ty1[8], tx2[8], ty2[8], ta[8];
#pragma unroll
    for (int j = 0; j < 8; j++) {
        tx1[j] = tb[j * 15 + 0]; ty1[j] = tb[j * 15 + 1];
        tx2[j] = tb[j * 15 + 2]; ty2[j] = tb[j * 15 + 3];
        ta[j] = (tx2[j] - tx1[j]) * (ty2[j] - ty1[j]);
    }
    const int pbase = chunk * 8192;
    float bi[8], bu[8]; unsigned int bp_[8];
#pragma unroll
    for (int j = 0; j < 8; j++) { bi[j] = 0.f; bu[j] = 1.f; bp_[j] = pbase + threadIdx.x; }
    for (int i = threadIdx.x; i < 8192; i += 256) {
        const int p = pbase + i;
        const float4 q = reinterpret_cast<const float4*>(priors)[p];
        const float px1 = q.x - q.z * 0.5f, py1 = q.y - q.w * 0.5f;
        const float px2 = q.x + q.z * 0.5f, py2 = q.y + q.w * 0.5f;
        const float areaB = (px2 - px1) * (py2 - py1);
#pragma unroll
        for (int j = 0; j < 8; j++) {
            float w = fminf(tx2[j], px2) - fmaxf(tx1[j], px1);
            float h = fminf(ty2[j], py2) - fmaxf(ty1[j], py1);
            w = fmaxf(w, 0.f); h = fmaxf(h, 0.f);
            float inter = w * h;
            float u = ta[j] + areaB - inter;
            if (inter * bu[j] > bi[j] * u) { bi[j] = inter; bu[j] = u; bp_[j] = (unsigned int)p; }
        }
    }
#pragma unroll
    for (int j = 0; j < 8; j++) {
        float iou = bi[j] / bu[j];
        unsigned long long key =
            ((unsigned long long)__float_as_uint(iou) << 32) | (unsigned long long)(~bp_[j]);
        for (int s = 32; s > 0; s >>= 1) {
            unsigned long long o = __shfl_down(key, s, 64);
            if (o > key) key = o;
        }
        if ((threadIdx.x & 63) == 0)
            atomicMax(&packed[b * NT + tg * 8 + j], key);
    }
}

// ---------------- Kernel C: per-prior match, encode, losses, lrank + fused hist1 ----------------
// grid (64, 16), block 1024
__global__ __launch_bounds__(1024) void kC(
    const float* __restrict__ loc_data, const float* __restrict__ conf_data,
    const float* __restrict__ landm_data, const float* __restrict__ priors,
    const float* __restrict__ targets, const unsigned long long* __restrict__ packed,
    float* __restrict__ lrank, unsigned int* __restrict__ hist1,
    float* __restrict__ accf, int* __restrict__ acci, int* __restrict__ npos) {
    const int b = blockIdx.y;
    const int p = blockIdx.x * 1024 + threadIdx.x;
    __shared__ unsigned int hist[2048];
    hist[threadIdx.x] = 0; hist[threadIdx.x + 1024] = 0;
    __syncthreads();

    const float4 q = reinterpret_cast<const float4*>(priors)[p];
    const float px1 = q.x - q.z * 0.5f, py1 = q.y - q.w * 0.5f;
    const float px2 = q.x + q.z * 0.5f, py2 = q.y + q.w * 0.5f;
    const float areaB = (px2 - px1) * (py2 - py1);

    // cross-multiplied running argmax over truths (uniform scalar loads, no LDS)
    const float* tb = targets + (size_t)b * NT * 15;
    float bi = 0.f, bu = 1.f; int bt = 0;
#pragma unroll
    for (int t = 0; t < NT; t++) {
        float x1 = tb[t * 15 + 0], y1 = tb[t * 15 + 1];
        float x2 = tb[t * 15 + 2], y2 = tb[t * 15 + 3];
        float w = fminf(x2, px2) - fmaxf(x1, px1);
        float h = fminf(y2, py2) - fmaxf(y1, py1);
        w = fmaxf(w, 0.f); h = fmaxf(h, 0.f);
        float inter = w * h;
        float u = (x2 - x1) * (y2 - y1) + areaB - inter;
        if (inter * bu > bi * u) { bi = inter; bu = u; bt = t; }
    }
    float bestov = bi / bu;

    // claim overwrite (ascending t: last claim wins, matches fori_loop)
    const unsigned long long* pk = packed + b * NT;
    int claimed = -1;
#pragma unroll
    for (int t = 0; t < NT; t++) {
        unsigned int pp = ~(unsigned int)(pk[t] & 0xFFFFFFFFull);
        if ((int)pp == p) claimed = t;
    }
    if (claimed >= 0) { bt = claimed; bestov = 2.f; }

    const float* tr = targets + ((size_t)b * NT + bt) * 15;
    const int confi = (bestov < TH) ? 0 : (int)tr[14];
    const bool pos = (confi != 0);
    const bool posl = (confi > 0);

    const float2 c2 = reinterpret_cast<const float2*>(conf_data)[(size_t)b * NP + p];
    float m = fmaxf(c2.x, c2.y);
    float lse = m + __logf(__expf(c2.x - m) + __expf(c2.y - m));
    float ce = lse - (pos ? c2.y : c2.x);
    float lr = pos ? 0.f : ce;
    lrank[(size_t)b * NP + p] = lr;
    atomicAdd(&hist[__float_as_uint(lr) >> 20], 1u);

    float sl = 0.f, slm = 0.f, cep = 0.f;
    if (pos) {
        cep = ce;
        float x1 = tr[0], y1 = tr[1], x2 = tr[2], y2 = tr[3];
        float izi = 1.f / (0.1f * q.z), iwi = 1.f / (0.1f * q.w);
        float gcx = ((x1 + x2) * 0.5f - q.x) * izi;
        float gcy = ((y1 + y2) * 0.5f - q.y) * iwi;
        float gw = __logf((x2 - x1) / q.z) * 5.f;
        float gh = __logf((y2 - y1) / q.w) * 5.f;
        float4 ld = reinterpret_cast<const float4*>(loc_data)[(size_t)b * NP + p];
        sl = sml1(ld.x - gcx) + sml1(ld.y - gcy) + sml1(ld.z - gw) + sml1(ld.w - gh);
        if (posl) {
            const float* lmd = landm_data + ((size_t)b * NP + p) * 10;
#pragma unroll
            for (int i = 0; i < 5; i++) {
                float gx = (tr[4 + 2 * i] - q.x) * izi;
                float gy = (tr[5 + 2 * i] - q.y) * iwi;
                slm += sml1(lmd[2 * i] - gx) + sml1(lmd[2 * i + 1] - gy);
            }
        }
    }

    int cp = pos ? 1 : 0, cpl = posl ? 1 : 0;
    for (int s = 32; s > 0; s >>= 1) {
        sl += __shfl_down(sl, s, 64);
        slm += __shfl_down(slm, s, 64);
        cep += __shfl_down(cep, s, 64);
        cp += __shfl_down(cp, s, 64);
        cpl += __shfl_down(cpl, s, 64);
    }
    __shared__ float rf[48];
    __shared__ int ri[32];
    const int lane = threadIdx.x & 63, w = threadIdx.x >> 6;
    if (lane == 0) { rf[w] = sl; rf[16 + w] = slm; rf[32 + w] = cep; ri[w] = cp; ri[16 + w] = cpl; }
    __syncthreads();  // covers both the reduce arrays and the LDS histogram
    if (threadIdx.x == 0) {
        float a = 0, bb = 0, c = 0; int d = 0, e = 0;
        for (int i = 0; i < 16; i++) { a += rf[i]; bb += rf[16 + i]; c += rf[32 + i]; d += ri[i]; e += ri[16 + i]; }
        atomicAdd(&accf[0], a);
        atomicAdd(&accf[1], bb);
        atomicAdd(&accf[2], c);
        if (d) { atomicAdd(&acci[0], d); atomicAdd(&npos[b], d); }
        if (e) atomicAdd(&acci[1], e);
    }
    // merge fused level-1 histogram
    unsigned int c0 = hist[threadIdx.x], c1 = hist[threadIdx.x + 1024];
    if (c0) atomicAdd(&hist1[b * 2048 + threadIdx.x], c0);
    if (c1) atomicAdd(&hist1[b * 2048 + threadIdx.x + 1024], c1);
}

// find the bin containing the k-th largest (descending scan). block must be 256.
__device__ __forceinline__ void find_bin_256(const unsigned int* __restrict__ gh,
                                             unsigned int k, unsigned int* part,
                                             int* r_bin, unsigned int* r_acc) {
    unsigned int s = 0;
#pragma unroll
    for (int i = 0; i < 8; i++) s += gh[threadIdx.x * 8 + i];
    part[threadIdx.x] = s;
    __syncthreads();
    if (threadIdx.x == 0) {
        unsigned int acc = 0; int g = 255;
        for (; g > 0; --g) { unsigned int pg = part[g]; if (acc + pg >= k) break; acc += pg; }
        int bin = g * 8;
        for (int i = 7; i >= 0; --i) {
            unsigned int c = gh[g * 8 + i];
            if (acc + c >= k) { bin = g * 8 + i; break; }
            acc += c;
        }
        *r_bin = bin; *r_acc = acc;  // acc = count strictly above bin
    }
    __syncthreads();
}

// ---------------- Kernel D3: level-2 histogram (bits 20..9) within level-1 bin ----------------
__global__ void kD3(const float* __restrict__ lrank, const unsigned int* __restrict__ hist1,
                    unsigned int* __restrict__ hist2, const int* __restrict__ npos) {
    const int b = blockIdx.y;
    int k = 7 * npos[b]; if (k > NP - 1) k = NP - 1;
    if (k <= 0) return;
    __shared__ unsigned int part[256];
    __shared__ int sbin;
    __shared__ unsigned int sacc;
    find_bin_256(hist1 + b * 2048, (unsigned int)k, part, &sbin, &sacc);
    __shared__ unsigned int h2[2048];
    for (int i = threadIdx.x; i < 2048; i += 256) h2[i] = 0;
    __syncthreads();
    const float* v = lrank + (size_t)b * NP;
    const int base = blockIdx.x * 4096;
    const unsigned int b1 = (unsigned int)sbin;
    for (int i = threadIdx.x; i < 4096; i += 256) {
        unsigned int u = __float_as_uint(v[base + i]);
        if ((u >> 20) == b1) atomicAdd(&h2[(u >> 9) & 2047], 1u);
    }
    __syncthreads();
    unsigned int* gh2 = hist2 + b * 2048;
    for (int i = threadIdx.x; i < 2048; i += 256) {
        unsigned int c = h2[i];
        if (c) atomicAdd(&gh2[i], c);
    }
}

// ---------------- Kernel D5: selective sum of top-k negatives ----------------
__global__ void kD5(const float* __restrict__ lrank, const unsigned int* __restrict__ hist1,
                    const unsigned int* __restrict__ hist2, const int* __restrict__ npos,
                    float* __restrict__ accf) {
    const int b = blockIdx.y;
    int k = 7 * npos[b]; if (k > NP - 1) k = NP - 1;
    if (k <= 0) return;
    __shared__ unsigned int part[256];
    __shared__ int sbin1, sbin2;
    __shared__ unsigned int sacc1, sacc2;
    find_bin_256(hist1 + b * 2048, (unsigned int)k, part, &sbin1, &sacc1);
    unsigned int k1 = (unsigned int)k - sacc1;
    find_bin_256(hist2 + b * 2048, k1, part, &sbin2, &sacc2);
    unsigned int k2 = k1 - sacc2;
    const unsigned int pfx = (((unsigned int)sbin1) << 11) | (unsigned int)sbin2;  // bits 30..9
    const float* v = lrank + (size_t)b * NP;
    const int base = blockIdx.x * 4096;
    float sum = 0.f;
    for (int i = threadIdx.x; i < 4096; i += 256) {
        float x = v[base + i];
        if ((__float_as_uint(x) >> 9) > pfx) sum += x;
    }
    for (int s = 32; s > 0; s >>= 1) sum += __shfl_down(sum, s, 64);
    __shared__ float wsum[4];
    const int lane = threadIdx.x & 63, w = threadIdx.x >> 6;
    if (lane == 0) wsum[w] = sum;
    __syncthreads();
    if (threadIdx.x == 0) {
        float tot = wsum[0] + wsum[1] + wsum[2] + wsum[3];
        if (blockIdx.x == 0)  // boundary-bin tie contribution, once per row
            tot += (float)k2 * __uint_as_float((pfx << 9) | 256u);
        if (tot != 0.f) atomicAdd(&accf[3], tot);
    }
}

// ---------------- Kernel E: finalize ----------------
__global__ void kE(const float* __restrict__ accf, const int* __restrict__ acci,
                   float* __restrict__ out) {
    if (threadIdx.x == 0) {
        float N = fmaxf((float)acci[0], 1.f);
        float N1 = fmaxf((float)acci[1], 1.f);
        out[0] = accf[0] / N;
        out[1] = (accf[2] + accf[3]) / N;
        out[2] = accf[1] / N1;
    }
}

extern "C" void kernel_launch(void* const* d_in, const int* in_sizes, int n_in,
                              void* d_out, int out_size, void* d_ws, size_t ws_size,
                              hipStream_t stream) {
    const float* loc_data = (const float*)d_in[0];
    const float* conf_data = (const float*)d_in[1];
    const float* landm_data = (const float*)d_in[2];
    const float* priors = (const float*)d_in[3];
    const float* targets = (const float*)d_in[4];
    float* out = (float*)d_out;
    char* ws = (char*)d_ws;
    float* accf = (float*)ws;
    int* acci = (int*)(ws + 16);
    int* npos = (int*)(ws + 24);
    unsigned long long* packed = (unsigned long long*)(ws + 128);
    unsigned int* hist1 = (unsigned int*)(ws + WS_HIST1);
    unsigned int* hist2 = (unsigned int*)(ws + WS_HIST2);
    float* lrank = (float*)(ws + WS_LRANK);

    hipMemsetAsync(d_ws, 0, WS_ZERO, stream);
    kA<<<dim3(8, 6, 16), 256, 0, stream>>>(priors, targets, packed);
    kC<<<dim3(64, 16), 1024, 0, stream>>>(loc_data, conf_data, landm_data, priors, targets,
                                          packed, lrank, hist1, accf, acci, npos);
    kD3<<<dim3(16, 16), 256, 0, stream>>>(lrank, hist1, hist2, npos);
    kD5<<<dim3(16, 16), 256, 0, stream>>>(lrank, hist1, hist2, npos, accf);
    kE<<<1, 64, 0, stream>>>(accf, acci, out);
}